// Round 13
// baseline (5355.113 us; speedup 1.0000x reference)
//
#include <hip/hip_runtime.h>
#include <math.h>

constexpr int HID  = 2048;
constexpr int NEXP = 128;
constexpr int TOPK = 8;
constexpr int BM   = 16;     // rows per block
constexpr int BK   = 32;     // k per chunk
constexpr int ROWS = 16384;
constexpr int NCHUNK = HID / BK;   // 64

typedef float f32x4 __attribute__((ext_vector_type(4)));
typedef float f32x2 __attribute__((ext_vector_type(2)));

// Round-6 structure (LDS-shared W: correct+fast-ish) with its two measured
// defects fixed:
//  - bank conflicts (7.5M): A stored [row][k]+pad, B stored k-major with a
//    split-half quad layout -> all main-loop reads <=2-way (free, m136).
//  - latency (2 blk/CU, barrier drain, 35% VALU): grid 1024 = 4 blocks/CU,
//    double-buffered LDS with ONE barrier per chunk, reg-prefetch issued
//    before compute and written after (T14).
// Thread = 1 row x 8 experts (8 indep fmaf chains); k ascending -> same
// accumulation pattern that passed rounds 6 and 12.
__global__ __launch_bounds__(256, 4)
void router_f32(const float* __restrict__ X, const float* __restrict__ W,
                float* __restrict__ out_w, float* __restrict__ out_i,
                float* __restrict__ out_l) {
    __shared__ float As[2][BM][BK + 4];      // [buf][row][k], pad 4
    __shared__ float Bs[2][BK][NEXP];        // [buf][k][quad layout]

    const int tid  = threadIdx.x;
    const int egrp = tid & 15;               // experts 8*egrp .. 8*egrp+7
    const int rgrp = tid >> 4;               // row 0..15 in tile
    const int row0 = blockIdx.x * BM;

    // X staging: thread loads X[row0+rgrp][kc + 2*egrp .. +1]  (f32x2)
    const float* __restrict__ xsrc = X + (size_t)(row0 + rgrp) * HID + 2 * egrp;
    // W staging: thread loads W[we][kc + 16*wk .. +15]  (4 x f32x4)
    const int we = tid & 127, wk = tid >> 7;
    const float* __restrict__ wsrc = W + (size_t)we * HID + 16 * wk;
    // B quad-layout float offset for expert we within a k-row:
    // e = 8g+4h+p  ->  off = 4g + 64h + p
    const int boff = 4 * (we >> 3) + 64 * ((we >> 2) & 1) + (we & 3);

    float acc[8] = {};

    // ---- prologue: stage chunk 0 ----
    {
        const f32x2 xa = *(const f32x2*)(xsrc);
        f32x4 wa[4];
        #pragma unroll
        for (int j = 0; j < 4; ++j) wa[j] = *(const f32x4*)(wsrc + 4 * j);
        As[0][rgrp][2 * egrp]     = xa[0];
        As[0][rgrp][2 * egrp + 1] = xa[1];
        #pragma unroll
        for (int j = 0; j < 4; ++j)
            #pragma unroll
            for (int i = 0; i < 4; ++i)
                Bs[0][16 * wk + 4 * j + i][boff] = wa[j][i];
    }
    __syncthreads();

    // ---- main loop: dbuf, 1 barrier per chunk ----
    int buf = 0;
    #pragma unroll 1
    for (int c = 0; c < NCHUNK; ++c) {
        f32x2 xn;
        f32x4 wn[4];
        if (c + 1 < NCHUNK) {                        // issue prefetch early
            xn = *(const f32x2*)(xsrc + (c + 1) * BK);
            const float* wp = wsrc + (c + 1) * BK;
            #pragma unroll
            for (int j = 0; j < 4; ++j) wn[j] = *(const f32x4*)(wp + 4 * j);
        }

        // compute chunk c
        #pragma unroll
        for (int k4 = 0; k4 < BK / 4; ++k4) {
            const f32x4 xa = *(const f32x4*)(&As[buf][rgrp][4 * k4]);
            #pragma unroll
            for (int kk = 0; kk < 4; ++kk) {
                const int k = 4 * k4 + kk;
                const f32x4 b0 = *(const f32x4*)(&Bs[buf][k][4 * egrp]);
                const f32x4 b1 = *(const f32x4*)(&Bs[buf][k][64 + 4 * egrp]);
                #pragma unroll
                for (int j = 0; j < 4; ++j) acc[j]     = fmaf(xa[kk], b0[j], acc[j]);
                #pragma unroll
                for (int j = 0; j < 4; ++j) acc[4 + j] = fmaf(xa[kk], b1[j], acc[4 + j]);
            }
        }

        // write prefetched chunk late (target buffer safe: barrier of c-1
        // guaranteed all waves finished reading it)
        if (c + 1 < NCHUNK) {
            As[buf ^ 1][rgrp][2 * egrp]     = xn[0];
            As[buf ^ 1][rgrp][2 * egrp + 1] = xn[1];
            #pragma unroll
            for (int j = 0; j < 4; ++j)
                #pragma unroll
                for (int i = 0; i < 4; ++i)
                    Bs[buf ^ 1][16 * wk + 4 * j + i][boff] = wn[j][i];
        }
        __syncthreads();
        buf ^= 1;
    }

    // ---- epilogue ----
    // acc[j] = logit[row0+rgrp][8*egrp + j]; write direct to global (coalesced)
    {
        float* dst = out_l + (size_t)(row0 + rgrp) * NEXP + 8 * egrp;
        f32x4 lo, hi;
        #pragma unroll
        for (int j = 0; j < 4; ++j) { lo[j] = acc[j]; hi[j] = acc[4 + j]; }
        *(f32x4*)(dst)     = lo;
        *(f32x4*)(dst + 4) = hi;
    }

    // stage logits for top-8 (reuse Bs[0] region: 16*132*4 B <= 16 KB)
    float* Ls = (float*)&Bs[0][0][0];
    {
        float* p = Ls + rgrp * 132 + 8 * egrp;
        #pragma unroll
        for (int j = 0; j < 8; ++j) p[j] = acc[j];
    }
    __syncthreads();

    // top-8 + renormalized weights (proven epilogue): one lane per row
    if (tid < BM) {
        float v[TOPK];
        int   ixs[TOPK];
        #pragma unroll
        for (int j = 0; j < TOPK; ++j) { v[j] = -INFINITY; ixs[j] = 0; }
        const float* lr = Ls + tid * 132;
        #pragma unroll 1
        for (int cb = 0; cb < 32; ++cb) {
            f32x4 q4 = *(const f32x4*)(lr + cb * 4);
            #pragma unroll
            for (int u = 0; u < 4; ++u) {
                float s = q4[u];
                if (s > v[TOPK - 1]) {            // strict >: stable lower-index tie-break
                    v[TOPK - 1] = s; ixs[TOPK - 1] = cb * 4 + u;
                    #pragma unroll
                    for (int j = TOPK - 1; j > 0; --j)
                        if (v[j] > v[j - 1]) {
                            float tv = v[j]; v[j] = v[j - 1]; v[j - 1] = tv;
                            int   ti = ixs[j]; ixs[j] = ixs[j - 1]; ixs[j - 1] = ti;
                        }
                }
            }
        }
        const float m = v[0];
        float ex[TOPK], sum = 0.f;
        #pragma unroll
        for (int j = 0; j < TOPK; ++j) { ex[j] = expf(v[j] - m); sum += ex[j]; }
        const size_t grow = (size_t)(row0 + tid);
        #pragma unroll
        for (int j = 0; j < TOPK; ++j) {
            out_w[grow * TOPK + j] = ex[j] / sum;
            out_i[grow * TOPK + j] = (float)ixs[j];
        }
    }
}

extern "C" void kernel_launch(void* const* d_in, const int* in_sizes, int n_in,
                              void* d_out, int out_size, void* d_ws, size_t ws_size,
                              hipStream_t stream) {
    const float* X = (const float*)d_in[0];
    const float* W = (const float*)d_in[1];
    float* out   = (float*)d_out;
    float* out_w = out;                                 // [16384, 8]
    float* out_i = out + (size_t)ROWS * TOPK;           // [16384, 8] indices as float
    float* out_l = out + (size_t)ROWS * TOPK * 2;       // [16384, 128]

    dim3 grid(ROWS / BM);                               // 1024 blocks = 4/CU
    router_f32<<<grid, 256, 0, stream>>>(X, W, out_w, out_i, out_l);
}